// Round 15
// baseline (1314.823 us; speedup 1.0000x reference)
//
#include <hip/hip_runtime.h>
#include <stdint.h>

#define BB 8
#define SS 1024
#define EE 1024
#define HH 16
#define HDD 64

typedef unsigned short u16_t;
typedef __attribute__((ext_vector_type(8))) short short8;
typedef __attribute__((ext_vector_type(4))) float f32x4;

__device__ __forceinline__ u16_t f2bf(float f){
    union { float f; uint32_t u; } v; v.f = f;
    return (u16_t)((v.u + 0x7fffu + ((v.u >> 16) & 1u)) >> 16);
}
__device__ __forceinline__ float bf2f(u16_t u){
    union { uint32_t u; float f; } v; v.u = ((uint32_t)u) << 16;
    return v.f;
}

__device__ __forceinline__ void gload_lds16(const void* g, void* l){
    __builtin_amdgcn_global_load_lds((const __attribute__((address_space(1))) unsigned int*)g,
                                     (__attribute__((address_space(3))) unsigned int*)l, 16, 0, 0);
}

#define MFMA16(a,b,c) __builtin_amdgcn_mfma_f32_16x16x32_bf16(a,b,c,0,0,0)

union U8 { short8 v; u16_t u[8]; };

// ---------------- f32 -> bf16 convert (vectorized, grid-stride) ----------------
__global__ __launch_bounds__(256) void cvt_f32_bf16(const float* __restrict__ in,
                                                    u16_t* __restrict__ out, int n8){
    int i = blockIdx.x * blockDim.x + threadIdx.x;
    int stride = gridDim.x * blockDim.x;
    for (; i < n8; i += stride){
        const float4* p = (const float4*)(in + (size_t)i * 8);
        float4 a = p[0], b = p[1];
        U8 o;
        o.u[0]=f2bf(a.x); o.u[1]=f2bf(a.y); o.u[2]=f2bf(a.z); o.u[3]=f2bf(a.w);
        o.u[4]=f2bf(b.x); o.u[5]=f2bf(b.y); o.u[6]=f2bf(b.z); o.u[7]=f2bf(b.w);
        *(short8*)(out + (size_t)i * 8) = o.v;
    }
}

// ---------------- mask int32 -> bf16 bias (0 or ~-1e9) ----------------
__global__ __launch_bounds__(256) void cvt_mask(const int* __restrict__ mask,
                                                u16_t* __restrict__ mb, int n8){
    int i = blockIdx.x * blockDim.x + threadIdx.x;
    int stride = gridDim.x * blockDim.x;
    for (; i < n8; i += stride){
        const int4* p = (const int4*)(mask + (size_t)i * 8);
        int4 a = p[0], b = p[1];
        U8 o;
        o.u[0]=a.x?0xCE6Eu:0u; o.u[1]=a.y?0xCE6Eu:0u; o.u[2]=a.z?0xCE6Eu:0u; o.u[3]=a.w?0xCE6Eu:0u;
        o.u[4]=b.x?0xCE6Eu:0u; o.u[5]=b.y?0xCE6Eu:0u; o.u[6]=b.z?0xCE6Eu:0u; o.u[7]=b.w?0xCE6Eu:0u;
        *(short8*)(mb + (size_t)i * 8) = o.v;
    }
}

// ---------------- V transpose: Vp[b*S+s][h*64+d] -> Vt[(b*16+h)*64+d][s] ----------------
__global__ __launch_bounds__(256) void transpose_v(const u16_t* __restrict__ Vp,
                                                   u16_t* __restrict__ Vt){
    __shared__ u16_t sT[64 * 66];
    const int b = blockIdx.z, h = blockIdx.y, s0 = blockIdx.x * 64;
    const int tid = threadIdx.x;
    #pragma unroll
    for (int it = 0; it < 2; it++){
        int c = it * 256 + tid;
        int sr = c >> 3, c8 = c & 7;
        short8 v = *(const short8*)(Vp + (size_t)(b * SS + s0 + sr) * EE + h * HDD + c8 * 8);
        *(short8*)(sT + sr * 66 + c8 * 8) = v;
    }
    __syncthreads();
    #pragma unroll
    for (int it = 0; it < 2; it++){
        int c = it * 256 + tid;
        int dr = c >> 3, c8 = c & 7;
        U8 o;
        #pragma unroll
        for (int e = 0; e < 8; e++) o.u[e] = sT[(c8 * 8 + e) * 66 + dr];
        *(short8*)(Vt + ((size_t)(b * HH + h) * HDD + dr) * SS + s0 + c8 * 8) = o.v;
    }
}

// ---------------- C[M,N] = A[M,K] * B[N,K]^T + bias ; 128x128 tile, BK=32 ----------------
template<bool OUTF32>
__global__ __launch_bounds__(256) void gemm_bt(const u16_t* __restrict__ A,
                                               const u16_t* __restrict__ Bw,
                                               const float* __restrict__ bias,
                                               void* __restrict__ Cout,
                                               int M, int N, int K)
{
    __shared__ u16_t sA[128 * 32];
    __shared__ u16_t sB[128 * 32];
    const int tid = threadIdx.x;
    const int wave = tid >> 6, lane = tid & 63;
    const int m0 = blockIdx.y * 128, n0 = blockIdx.x * 128;
    const int wm = (wave >> 1) * 64, wn = (wave & 1) * 64;

    f32x4 acc[4][4] = {};

    for (int k0 = 0; k0 < K; k0 += 32){
        #pragma unroll
        for (int i = 0; i < 2; i++){
            int s   = (wave * 2 + i) * 64 + lane;
            int row = s >> 2, cb = (s & 3) * 8;
            gload_lds16(A  + (size_t)(m0 + row) * K + k0 + cb, (void*)(sA + (wave * 2 + i) * 512));
            gload_lds16(Bw + (size_t)(n0 + row) * K + k0 + cb, (void*)(sB + (wave * 2 + i) * 512));
        }
        __syncthreads();

        short8 aF[4], bF[4];
        #pragma unroll
        for (int m = 0; m < 4; m++)
            aF[m] = *(const short8*)(sA + (wm + m * 16 + (lane & 15)) * 32 + (lane >> 4) * 8);
        #pragma unroll
        for (int n = 0; n < 4; n++)
            bF[n] = *(const short8*)(sB + (wn + n * 16 + (lane & 15)) * 32 + (lane >> 4) * 8);
        #pragma unroll
        for (int m = 0; m < 4; m++)
            #pragma unroll
            for (int n = 0; n < 4; n++)
                acc[m][n] = MFMA16(aF[m], bF[n], acc[m][n]);
        __syncthreads();
    }

    #pragma unroll
    for (int m = 0; m < 4; m++){
        #pragma unroll
        for (int n = 0; n < 4; n++){
            int col = n0 + wn + n * 16 + (lane & 15);
            float bv = bias[col];
            #pragma unroll
            for (int j = 0; j < 4; j++){
                int row = m0 + wm + m * 16 + (lane >> 4) * 4 + j;
                float v = acc[m][n][j] + bv;
                if (OUTF32) ((float*)Cout)[(size_t)row * N + col] = v;
                else        ((u16_t*)Cout)[(size_t)row * N + col] = f2bf(v);
            }
        }
    }
}

// ---------------- fused attention, two sweeps, BARRIER-FREE main loops ----------------
// grid 2048 1D; decode: b = flat&7 (== XCD), i0 = ((flat>>3)&15)*64 (fastest), h outer
// (R12 clean-write decode). K and V^T slices per (b,h) are 128 KB each and shared by 16
// co-resident blocks -> L2-hot -> read DIRECTLY from global as MFMA fragments (16B/lane;
// lanes {fks=0..3} of one frow cover 64B contiguous). No K/V LDS staging => no barriers
// in the main loops. All remaining LDS use (Q stage, P write/read, attn store) is
// wave-private by rows [16w,16w+16): ordering needs only an intra-wave memory fence
// (__threadfence_block), never __syncthreads. 12-16 free-running waves/CU hide latency.
// No launch_bounds min-waves: (256,N>=4) makes the allocator cap VGPRs at ~256/N and
// spill mbv/adjv to scratch (R13/R14: +500MB traffic, 2x slower).
__global__ __launch_bounds__(256) void attn_fused(const u16_t* __restrict__ Qp,
                                                  const u16_t* __restrict__ Kp,
                                                  const u16_t* __restrict__ Vt,
                                                  const u16_t* __restrict__ maskb,
                                                  const float* __restrict__ adjoin,
                                                  float* __restrict__ attn,
                                                  u16_t* __restrict__ X)
{
    __shared__ u16_t sPB[64 * 64];   // 8 KB: Q staging, then P tiles; wave-private rows

    const int flat = blockIdx.x;
    const int b  = flat & 7;
    const int i0 = ((flat >> 3) & 15) * 64;
    const int h  = flat >> 7;
    const int tid = threadIdx.x, wave = tid >> 6, lane = tid & 63;
    const int frow = lane & 15, fks = lane >> 4;
    const int bh = b * HH + h;

    // ---- stage Q tile (swizzled, wave-private rows) into sPB, extract fragments
    #pragma unroll
    for (int i = 0; i < 2; i++){
        int chunk = (wave * 2 + i) * 64 + lane;
        int row = chunk >> 3, slot = chunk & 7;
        gload_lds16(Qp + (size_t)(b * SS + i0 + row) * EE + h * HDD + (slot ^ (row & 7)) * 8,
                    (void*)(sPB + (wave * 2 + i) * 512));
    }
    __syncthreads();                 // one-time; drains gload_lds
    short8 aQ0, aQ1;
    {
        int row = wave * 16 + frow;
        aQ0 = *(const short8*)((const char*)sPB + row * 128 + ((fks * 16)      ^ ((row & 7) << 4)));
        aQ1 = *(const short8*)((const char*)sPB + row * 128 + ((64 + fks * 16) ^ ((row & 7) << 4)));
    }
    __threadfence_block();           // Q reads complete before sPB rows are overwritten (wave-private)

    const u16_t* Kb = Kp + (size_t)b * SS * EE + h * HDD;   // K row j at Kb + j*EE
    const u16_t* Vb = Vt + (size_t)bh * HDD * SS;           // V^T row d at Vb + d*SS

    const int grow0 = i0 + wave * 16 + fks * 4;
    const size_t mrowbase = (size_t)(b * SS + grow0) * SS;   // + r*SS + col

    // ================= sweep 1: rowsums of exp (no LDS, no barriers) =================
    float s_run[4] = {0.f, 0.f, 0.f, 0.f};
    #pragma unroll
    for (int t = 0; t < 16; t++){
        // K fragments direct from global (L2-hot)
        short8 kf0[4], kf1[4];
        #pragma unroll
        for (int n = 0; n < 4; n++){
            const u16_t* kr = Kb + (size_t)(t * 64 + n * 16 + frow) * EE + fks * 8;
            kf0[n] = *(const short8*)(kr);
            kf1[n] = *(const short8*)(kr + 32);
        }
        float mbv[4][4];
        #pragma unroll
        for (int n = 0; n < 4; n++)
            #pragma unroll
            for (int r = 0; r < 4; r++)
                mbv[n][r] = bf2f(maskb[mrowbase + (size_t)r * SS + t * 64 + n * 16 + frow]);
        __builtin_amdgcn_s_setprio(1);
        #pragma unroll
        for (int n = 0; n < 4; n++){
            f32x4 acc = {};
            acc = MFMA16(aQ0, kf0[n], acc);
            acc = MFMA16(aQ1, kf1[n], acc);
            #pragma unroll
            for (int r = 0; r < 4; r++)
                s_run[r] += __expf(acc[r] * 0.125f + mbv[n][r]);
        }
        __builtin_amdgcn_s_setprio(0);
    }
    float inv[4];
    #pragma unroll
    for (int r = 0; r < 4; r++){
        float v = s_run[r];
        v += __shfl_xor(v, 1); v += __shfl_xor(v, 2); v += __shfl_xor(v, 4); v += __shfl_xor(v, 8);
        inv[r] = 1.0f / v;
    }

    // ================= sweep 2: att = exp*inv + adjoin ; PV ; attn store =================
    f32x4 accPV[4] = {};
    #pragma unroll
    for (int t = 0; t < 16; t++){
        short8 kf0[4], kf1[4];
        #pragma unroll
        for (int n = 0; n < 4; n++){
            const u16_t* kr = Kb + (size_t)(t * 64 + n * 16 + frow) * EE + fks * 8;
            kf0[n] = *(const short8*)(kr);
            kf1[n] = *(const short8*)(kr + 32);
        }
        float mbv[4][4], adjv[4][4];
        #pragma unroll
        for (int n = 0; n < 4; n++)
            #pragma unroll
            for (int r = 0; r < 4; r++){
                size_t off = mrowbase + (size_t)r * SS + t * 64 + n * 16 + frow;
                mbv[n][r]  = bf2f(maskb[off]);
                adjv[n][r] = adjoin[off];
            }
        __builtin_amdgcn_s_setprio(1);
        #pragma unroll
        for (int n = 0; n < 4; n++){
            f32x4 acc = {};
            acc = MFMA16(aQ0, kf0[n], acc);
            acc = MFMA16(aQ1, kf1[n], acc);
            #pragma unroll
            for (int r = 0; r < 4; r++){
                int irow = wave * 16 + fks * 4 + r;
                float att = __expf(acc[r] * 0.125f + mbv[n][r]) * inv[r] + adjv[n][r];
                *(u16_t*)((char*)sPB + irow * 128 + (((n * 16 + frow) * 2) ^ ((irow & 7) << 4))) = f2bf(att);
            }
        }
        __builtin_amdgcn_s_setprio(0);

        __threadfence_block();              // intra-wave: sPB writes ordered before reads
        asm volatile("" ::: "memory");

        // PV MFMA: accPV[n] += att(16i x 64j) * V^T(16d x 64j); V direct from global
        __builtin_amdgcn_s_setprio(1);
        {
            int prow = wave * 16 + frow;
            short8 aP0 = *(const short8*)((const char*)sPB + prow * 128 + ((fks * 16)      ^ ((prow & 7) << 4)));
            short8 aP1 = *(const short8*)((const char*)sPB + prow * 128 + ((64 + fks * 16) ^ ((prow & 7) << 4)));
            #pragma unroll
            for (int n = 0; n < 4; n++){
                const u16_t* vr = Vb + (size_t)(n * 16 + frow) * SS + t * 64 + fks * 8;
                short8 bV0 = *(const short8*)(vr);
                short8 bV1 = *(const short8*)(vr + 32);
                accPV[n] = MFMA16(aP0, bV0, accPV[n]);
                accPV[n] = MFMA16(aP1, bV1, accPV[n]);
            }
        }
        __builtin_amdgcn_s_setprio(0);

        // attn store from sPB, wave-private rows: 4 lanes x 16B = 64B contiguous per row
        {
            int row = wave * 16 + (lane >> 2);
            int l4  = lane & 3;
            float* dstrow = attn + ((size_t)bh * SS + i0 + row) * SS + t * 64;
            #pragma unroll
            for (int cc = 0; cc < 4; cc++){
                int colb = cc * 32 + l4 * 8;   // byte offset within the 128B sPB row
                uint2 pv = *(const uint2*)((const char*)sPB + row * 128 + (colb ^ ((row & 7) << 4)));
                float4 o;
                o.x = bf2f((u16_t)(pv.x & 0xffffu));
                o.y = bf2f((u16_t)(pv.x >> 16));
                o.z = bf2f((u16_t)(pv.y & 0xffffu));
                o.w = bf2f((u16_t)(pv.y >> 16));
                *(float4*)(dstrow + cc * 16 + l4 * 4) = o;
            }
        }
        __threadfence_block();              // store reads done before next tile's sPB writes
        asm volatile("" ::: "memory");
    }

    // ---- X write (bf16): att@V already includes adjoin contribution
    #pragma unroll
    for (int n = 0; n < 4; n++){
        #pragma unroll
        for (int j = 0; j < 4; j++){
            int row = i0 + wave * 16 + fks * 4 + j;
            int col = h * HDD + n * 16 + frow;
            X[(size_t)(b * SS + row) * EE + col] = f2bf(accPV[n][j]);
        }
    }
}

extern "C" void kernel_launch(void* const* d_in, const int* in_sizes, int n_in,
                              void* d_out, int out_size, void* d_ws, size_t ws_size,
                              hipStream_t stream)
{
    const float* query  = (const float*)d_in[0];
    const float* key    = (const float*)d_in[1];
    const float* value  = (const float*)d_in[2];
    const int*   mask   = (const int*)  d_in[3];
    const float* adjoin = (const float*)d_in[4];
    const float* Wq = (const float*)d_in[5];
    const float* bq = (const float*)d_in[6];
    const float* Wk = (const float*)d_in[7];
    const float* bk = (const float*)d_in[8];
    const float* Wv = (const float*)d_in[9];
    const float* bv = (const float*)d_in[10];
    const float* Wo = (const float*)d_in[11];
    const float* bo = (const float*)d_in[12];

    float* out  = (float*)d_out;
    float* attn = out + (size_t)BB * SS * EE;

    const size_t nBSE = (size_t)BB * SS * EE;   // 8388608 (== B*S*S)
    const size_t nEE  = (size_t)EE * EE;        // 1048576

    u16_t* p  = (u16_t*)d_ws;
    u16_t* qb  = p; p += nBSE;
    u16_t* kb  = p; p += nBSE;
    u16_t* vb  = p; p += nBSE;
    u16_t* Qp  = p; p += nBSE;
    u16_t* Kp  = p; p += nBSE;
    u16_t* Vp  = p; p += nBSE;
    u16_t* Xa  = p; p += nBSE;
    u16_t* Wqb = p; p += nEE;
    u16_t* Wkb = p; p += nEE;
    u16_t* Wvb = p; p += nEE;
    u16_t* Wob = p; p += nEE;

    // dead-region reuse after projections: Vt <- qb, maskb <- kb
    u16_t* Vt    = qb;
    u16_t* maskb = kb;

    cvt_f32_bf16<<<1024, 256, 0, stream>>>(query, qb, (int)(nBSE / 8));
    cvt_f32_bf16<<<1024, 256, 0, stream>>>(key,   kb, (int)(nBSE / 8));
    cvt_f32_bf16<<<1024, 256, 0, stream>>>(value, vb, (int)(nBSE / 8));
    cvt_f32_bf16<<<256,  256, 0, stream>>>(Wq, Wqb, (int)(nEE / 8));
    cvt_f32_bf16<<<256,  256, 0, stream>>>(Wk, Wkb, (int)(nEE / 8));
    cvt_f32_bf16<<<256,  256, 0, stream>>>(Wv, Wvb, (int)(nEE / 8));
    cvt_f32_bf16<<<256,  256, 0, stream>>>(Wo, Wob, (int)(nEE / 8));

    dim3 gProj(EE / 128, (BB * SS) / 128);   // (8, 64)
    gemm_bt<false><<<gProj, 256, 0, stream>>>(qb, Wqb, bq, (void*)Qp, BB * SS, EE, EE);
    gemm_bt<false><<<gProj, 256, 0, stream>>>(kb, Wkb, bk, (void*)Kp, BB * SS, EE, EE);
    gemm_bt<false><<<gProj, 256, 0, stream>>>(vb, Wvb, bv, (void*)Vp, BB * SS, EE, EE);

    dim3 gT(SS / 64, HH, BB);
    transpose_v<<<gT, 256, 0, stream>>>(Vp, Vt);
    cvt_mask<<<1024, 256, 0, stream>>>(mask, maskb, (int)(nBSE / 8));

    attn_fused<<<2048, 256, 0, stream>>>(Qp, Kp, Vt, maskb, adjoin, attn, Xa);

    gemm_bt<true><<<gProj, 256, 0, stream>>>(Xa, Wob, bo, (void*)out, BB * SS, EE, EE);
}

// Round 16
// 531.742 us; speedup vs baseline: 2.4727x; 2.4727x over previous
//
#include <hip/hip_runtime.h>
#include <stdint.h>

#define BB 8
#define SS 1024
#define EE 1024
#define HH 16
#define HDD 64

typedef unsigned short u16_t;
typedef __attribute__((ext_vector_type(8))) short short8;
typedef __attribute__((ext_vector_type(4))) float f32x4;

__device__ __forceinline__ u16_t f2bf(float f){
    union { float f; uint32_t u; } v; v.f = f;
    return (u16_t)((v.u + 0x7fffu + ((v.u >> 16) & 1u)) >> 16);
}
__device__ __forceinline__ float bf2f(u16_t u){
    union { uint32_t u; float f; } v; v.u = ((uint32_t)u) << 16;
    return v.f;
}

__device__ __forceinline__ void gload_lds16(const void* g, void* l){
    __builtin_amdgcn_global_load_lds((const __attribute__((address_space(1))) unsigned int*)g,
                                     (__attribute__((address_space(3))) unsigned int*)l, 16, 0, 0);
}

#define MFMA16(a,b,c) __builtin_amdgcn_mfma_f32_16x16x32_bf16(a,b,c,0,0,0)

union U8 { short8 v; u16_t u[8]; };

// ---------------- f32 -> bf16 convert (vectorized, grid-stride) ----------------
__global__ __launch_bounds__(256) void cvt_f32_bf16(const float* __restrict__ in,
                                                    u16_t* __restrict__ out, int n8){
    int i = blockIdx.x * blockDim.x + threadIdx.x;
    int stride = gridDim.x * blockDim.x;
    for (; i < n8; i += stride){
        const float4* p = (const float4*)(in + (size_t)i * 8);
        float4 a = p[0], b = p[1];
        U8 o;
        o.u[0]=f2bf(a.x); o.u[1]=f2bf(a.y); o.u[2]=f2bf(a.z); o.u[3]=f2bf(a.w);
        o.u[4]=f2bf(b.x); o.u[5]=f2bf(b.y); o.u[6]=f2bf(b.z); o.u[7]=f2bf(b.w);
        *(short8*)(out + (size_t)i * 8) = o.v;
    }
}

// ---------------- mask int32 -> bf16 bias (0 or ~-1e9) ----------------
__global__ __launch_bounds__(256) void cvt_mask(const int* __restrict__ mask,
                                                u16_t* __restrict__ mb, int n8){
    int i = blockIdx.x * blockDim.x + threadIdx.x;
    int stride = gridDim.x * blockDim.x;
    for (; i < n8; i += stride){
        const int4* p = (const int4*)(mask + (size_t)i * 8);
        int4 a = p[0], b = p[1];
        U8 o;
        o.u[0]=a.x?0xCE6Eu:0u; o.u[1]=a.y?0xCE6Eu:0u; o.u[2]=a.z?0xCE6Eu:0u; o.u[3]=a.w?0xCE6Eu:0u;
        o.u[4]=b.x?0xCE6Eu:0u; o.u[5]=b.y?0xCE6Eu:0u; o.u[6]=b.z?0xCE6Eu:0u; o.u[7]=b.w?0xCE6Eu:0u;
        *(short8*)(mb + (size_t)i * 8) = o.v;
    }
}

// ---------------- V transpose: Vp[b*S+s][h*64+d] -> Vt[(b*16+h)*64+d][s] ----------------
__global__ __launch_bounds__(256) void transpose_v(const u16_t* __restrict__ Vp,
                                                   u16_t* __restrict__ Vt){
    __shared__ u16_t sT[64 * 66];
    const int b = blockIdx.z, h = blockIdx.y, s0 = blockIdx.x * 64;
    const int tid = threadIdx.x;
    #pragma unroll
    for (int it = 0; it < 2; it++){
        int c = it * 256 + tid;
        int sr = c >> 3, c8 = c & 7;
        short8 v = *(const short8*)(Vp + (size_t)(b * SS + s0 + sr) * EE + h * HDD + c8 * 8);
        *(short8*)(sT + sr * 66 + c8 * 8) = v;
    }
    __syncthreads();
    #pragma unroll
    for (int it = 0; it < 2; it++){
        int c = it * 256 + tid;
        int dr = c >> 3, c8 = c & 7;
        U8 o;
        #pragma unroll
        for (int e = 0; e < 8; e++) o.u[e] = sT[(c8 * 8 + e) * 66 + dr];
        *(short8*)(Vt + ((size_t)(b * HH + h) * HDD + dr) * SS + s0 + c8 * 8) = o.v;
    }
}

// ---------------- C[M,N] = A[M,K] * B[N,K]^T + bias ; 128x128 tile, BK=32 ----------------
template<bool OUTF32>
__global__ __launch_bounds__(256) void gemm_bt(const u16_t* __restrict__ A,
                                               const u16_t* __restrict__ Bw,
                                               const float* __restrict__ bias,
                                               void* __restrict__ Cout,
                                               int M, int N, int K)
{
    __shared__ u16_t sA[128 * 32];
    __shared__ u16_t sB[128 * 32];
    const int tid = threadIdx.x;
    const int wave = tid >> 6, lane = tid & 63;
    const int m0 = blockIdx.y * 128, n0 = blockIdx.x * 128;
    const int wm = (wave >> 1) * 64, wn = (wave & 1) * 64;

    f32x4 acc[4][4] = {};

    for (int k0 = 0; k0 < K; k0 += 32){
        #pragma unroll
        for (int i = 0; i < 2; i++){
            int s   = (wave * 2 + i) * 64 + lane;
            int row = s >> 2, cb = (s & 3) * 8;
            gload_lds16(A  + (size_t)(m0 + row) * K + k0 + cb, (void*)(sA + (wave * 2 + i) * 512));
            gload_lds16(Bw + (size_t)(n0 + row) * K + k0 + cb, (void*)(sB + (wave * 2 + i) * 512));
        }
        __syncthreads();

        short8 aF[4], bF[4];
        #pragma unroll
        for (int m = 0; m < 4; m++)
            aF[m] = *(const short8*)(sA + (wm + m * 16 + (lane & 15)) * 32 + (lane >> 4) * 8);
        #pragma unroll
        for (int n = 0; n < 4; n++)
            bF[n] = *(const short8*)(sB + (wn + n * 16 + (lane & 15)) * 32 + (lane >> 4) * 8);
        #pragma unroll
        for (int m = 0; m < 4; m++)
            #pragma unroll
            for (int n = 0; n < 4; n++)
                acc[m][n] = MFMA16(aF[m], bF[n], acc[m][n]);
        __syncthreads();
    }

    #pragma unroll
    for (int m = 0; m < 4; m++){
        #pragma unroll
        for (int n = 0; n < 4; n++){
            int col = n0 + wn + n * 16 + (lane & 15);
            float bv = bias[col];
            #pragma unroll
            for (int j = 0; j < 4; j++){
                int row = m0 + wm + m * 16 + (lane >> 4) * 4 + j;
                float v = acc[m][n][j] + bv;
                if (OUTF32) ((float*)Cout)[(size_t)row * N + col] = v;
                else        ((u16_t*)Cout)[(size_t)row * N + col] = f2bf(v);
            }
        }
    }
}

// ---------------- fused attention, two sweeps, 32KB LDS ----------------
// grid 2048 1D; decode: b = flat&7 (== XCD), i0 = ((flat>>3)&15)*64 (FASTEST within XCD),
// h = flat>>7 (outer). Co-resident blocks share one (b,h) K/V slice (L2-hot) and write
// ADJACENT attn chunks -- R12-proven clean-write configuration (WRITE 610 MB).
// LDS 32KB: K double-buffered (2x8KB, stageK(t+1) at TOP), VT SINGLE (8KB, stageVT(t)
// at TOP, consumed after MID; prev PV reads done before TOP barrier), sPB 8KB
// -> 5 blocks/CU by LDS. __launch_bounds__(256,3): keeps the allocator at ~84 VGPR
// (R12-proven, no spill). R13's identical structure regressed ONLY because (256,5)
// collapsed VGPR to 48 -> mbv/adjv scratch spill (+600MB traffic). R14: (256,4)->64 also
// spilled. R15: no bound -> 256 VGPR, 1 block/CU. 84 VGPR @ (256,3) is the sweet spot.
__global__ __launch_bounds__(256, 3) void attn_fused(const u16_t* __restrict__ Qp,
                                                     const u16_t* __restrict__ Kp,
                                                     const u16_t* __restrict__ Vt,
                                                     const u16_t* __restrict__ maskb,
                                                     const float* __restrict__ adjoin,
                                                     float* __restrict__ attn,
                                                     u16_t* __restrict__ X)
{
    __shared__ u16_t sK[2][64 * 64];
    __shared__ u16_t sVT[64 * 64];
    __shared__ u16_t sPB[64 * 64];

    const int flat = blockIdx.x;
    const int b  = flat & 7;
    const int i0 = ((flat >> 3) & 15) * 64;
    const int h  = flat >> 7;
    const int tid = threadIdx.x, wave = tid >> 6, lane = tid & 63;
    const int frow = lane & 15, fks = lane >> 4;
    const int bh = b * HH + h;

    // ---- stage Q tile (swizzled) into sPB, extract fragments
    #pragma unroll
    for (int i = 0; i < 2; i++){
        int chunk = (wave * 2 + i) * 64 + lane;
        int row = chunk >> 3, slot = chunk & 7;
        gload_lds16(Qp + (size_t)(b * SS + i0 + row) * EE + h * HDD + (slot ^ (row & 7)) * 8,
                    (void*)(sPB + (wave * 2 + i) * 512));
    }
    __syncthreads();
    short8 aQ0, aQ1;
    {
        int row = wave * 16 + frow;
        aQ0 = *(const short8*)((const char*)sPB + row * 128 + ((fks * 16)      ^ ((row & 7) << 4)));
        aQ1 = *(const short8*)((const char*)sPB + row * 128 + ((64 + fks * 16) ^ ((row & 7) << 4)));
    }
    __syncthreads();

    auto stageK = [&](int j0, int buf){
        #pragma unroll
        for (int i = 0; i < 2; i++){
            int chunk = (wave * 2 + i) * 64 + lane;
            int row = chunk >> 3, slot = chunk & 7;
            gload_lds16(Kp + (size_t)(b * SS + j0 + row) * EE + h * HDD + (slot ^ (row & 7)) * 8,
                        (void*)(sK[buf] + (wave * 2 + i) * 512));
        }
    };
    auto stageVT = [&](int j0){
        #pragma unroll
        for (int i = 0; i < 2; i++){
            int chunk = (wave * 2 + i) * 64 + lane;
            int row = chunk >> 3, slot = chunk & 7;
            gload_lds16(Vt + ((size_t)bh * HDD + row) * SS + j0 + (slot ^ (row & 7)) * 8,
                        (void*)(sVT + (wave * 2 + i) * 512));
        }
    };

    const int grow0 = i0 + wave * 16 + fks * 4;
    const size_t mrowbase = (size_t)(b * SS + grow0) * SS;   // + r*SS + col

    // ================= sweep 1: rowsums of exp (K ping-pong) =================
    float s_run[4] = {0.f, 0.f, 0.f, 0.f};
    stageK(0, 0);
    #pragma unroll
    for (int t = 0; t < 16; t++){
        const int cur = t & 1;
        __syncthreads();                       // stage(t) arrived
        if (t < 15) stageK((t + 1) * 64, cur ^ 1);
        // mask bias fragments for tile t (scalar loads, L2/L3-resident)
        float mbv[4][4];
        #pragma unroll
        for (int n = 0; n < 4; n++)
            #pragma unroll
            for (int r = 0; r < 4; r++)
                mbv[n][r] = bf2f(maskb[mrowbase + (size_t)r * SS + t * 64 + n * 16 + frow]);
        __builtin_amdgcn_s_setprio(1);
        #pragma unroll
        for (int n = 0; n < 4; n++){
            int jrow = n * 16 + frow;
            f32x4 acc = {};
            short8 bF = *(const short8*)((const char*)sK[cur] + jrow * 128 + ((fks * 16)      ^ ((jrow & 7) << 4)));
            acc = MFMA16(aQ0, bF, acc);
            bF        = *(const short8*)((const char*)sK[cur] + jrow * 128 + ((64 + fks * 16) ^ ((jrow & 7) << 4)));
            acc = MFMA16(aQ1, bF, acc);
            #pragma unroll
            for (int r = 0; r < 4; r++)
                s_run[r] += __expf(acc[r] * 0.125f + mbv[n][r]);
        }
        __builtin_amdgcn_s_setprio(0);
    }
    float inv[4];
    #pragma unroll
    for (int r = 0; r < 4; r++){
        float v = s_run[r];
        v += __shfl_xor(v, 1); v += __shfl_xor(v, 2); v += __shfl_xor(v, 4); v += __shfl_xor(v, 8);
        inv[r] = 1.0f / v;
    }

    // ================= sweep 2: att = exp*inv + adjoin ; PV ; attn store =================
    // K double-buffered (stageK(t+1) at TOP, full-tile cover); VT single-buffered
    // (stageVT(t) at TOP, consumed after MID; cover = QK+exp phase).
    f32x4 accPV[4] = {};
    __syncthreads();                           // sweep-1 prefetches drained; buffers free
    stageK(0, 0);
    #pragma unroll
    for (int t = 0; t < 16; t++){
        const int cur = t & 1;
        __syncthreads();                       // TOP: K(t) arrived; prev-tile sVT/sPB reads done
        if (t < 15) stageK((t + 1) * 64, cur ^ 1);
        stageVT(t * 64);
        // hoisted mask + adjoin fragment loads (consumed after MFMA+exp chain)
        float mbv[4][4], adjv[4][4];
        #pragma unroll
        for (int n = 0; n < 4; n++)
            #pragma unroll
            for (int r = 0; r < 4; r++){
                size_t off = mrowbase + (size_t)r * SS + t * 64 + n * 16 + frow;
                mbv[n][r]  = bf2f(maskb[off]);
                adjv[n][r] = adjoin[off];
            }
        __builtin_amdgcn_s_setprio(1);
        #pragma unroll
        for (int n = 0; n < 4; n++){
            int jrow = n * 16 + frow;
            f32x4 acc = {};
            short8 bF = *(const short8*)((const char*)sK[cur] + jrow * 128 + ((fks * 16)      ^ ((jrow & 7) << 4)));
            acc = MFMA16(aQ0, bF, acc);
            bF        = *(const short8*)((const char*)sK[cur] + jrow * 128 + ((64 + fks * 16) ^ ((jrow & 7) << 4)));
            acc = MFMA16(aQ1, bF, acc);
            #pragma unroll
            for (int r = 0; r < 4; r++){
                int irow = wave * 16 + fks * 4 + r;
                float att = __expf(acc[r] * 0.125f + mbv[n][r]) * inv[r] + adjv[n][r];
                *(u16_t*)((char*)sPB + irow * 128 + (((n * 16 + frow) * 2) ^ ((irow & 7) << 4))) = f2bf(att);
            }
        }
        __builtin_amdgcn_s_setprio(0);
        __syncthreads();                       // MID: VT(t)+K(t+1) arrived; sPB visible
        // PV MFMA: accPV[n] += att(16i x 64j) * V^T(16d x 64j)
        __builtin_amdgcn_s_setprio(1);
        {
            int prow = wave * 16 + frow;
            short8 aP0 = *(const short8*)((const char*)sPB + prow * 128 + ((fks * 16)      ^ ((prow & 7) << 4)));
            short8 aP1 = *(const short8*)((const char*)sPB + prow * 128 + ((64 + fks * 16) ^ ((prow & 7) << 4)));
            #pragma unroll
            for (int n = 0; n < 4; n++){
                int drow = n * 16 + frow;
                short8 bV0 = *(const short8*)((const char*)sVT + drow * 128 + ((fks * 16)      ^ ((drow & 7) << 4)));
                short8 bV1 = *(const short8*)((const char*)sVT + drow * 128 + ((64 + fks * 16) ^ ((drow & 7) << 4)));
                accPV[n] = MFMA16(aP0, bV0, accPV[n]);
                accPV[n] = MFMA16(aP1, bV1, accPV[n]);
            }
        }
        __builtin_amdgcn_s_setprio(0);
        // attn store: PLAIN float4, 16 lanes x 16B = 256B contiguous per row
        {
            int rr = tid >> 4, c4 = tid & 15;
            #pragma unroll
            for (int it = 0; it < 4; it++){
                int row = it * 16 + rr;
                uint2 pv = *(const uint2*)((const char*)sPB + row * 128 + ((c4 * 8) ^ ((row & 7) << 4)));
                float4 o;
                o.x = bf2f((u16_t)(pv.x & 0xffffu));
                o.y = bf2f((u16_t)(pv.x >> 16));
                o.z = bf2f((u16_t)(pv.y & 0xffffu));
                o.w = bf2f((u16_t)(pv.y >> 16));
                *(float4*)(attn + ((size_t)bh * SS + i0 + row) * SS + t * 64 + c4 * 4) = o;
            }
        }
    }

    // ---- X write (bf16): att@V already includes adjoin contribution
    #pragma unroll
    for (int n = 0; n < 4; n++){
        #pragma unroll
        for (int j = 0; j < 4; j++){
            int row = i0 + wave * 16 + fks * 4 + j;
            int col = h * HDD + n * 16 + frow;
            X[(size_t)(b * SS + row) * EE + col] = f2bf(accPV[n][j]);
        }
    }
}

extern "C" void kernel_launch(void* const* d_in, const int* in_sizes, int n_in,
                              void* d_out, int out_size, void* d_ws, size_t ws_size,
                              hipStream_t stream)
{
    const float* query  = (const float*)d_in[0];
    const float* key    = (const float*)d_in[1];
    const float* value  = (const float*)d_in[2];
    const int*   mask   = (const int*)  d_in[3];
    const float* adjoin = (const float*)d_in[4];
    const float* Wq = (const float*)d_in[5];
    const float* bq = (const float*)d_in[6];
    const float* Wk = (const float*)d_in[7];
    const float* bk = (const float*)d_in[8];
    const float* Wv = (const float*)d_in[9];
    const float* bv = (const float*)d_in[10];
    const float* Wo = (const float*)d_in[11];
    const float* bo = (const float*)d_in[12];

    float* out  = (float*)d_out;
    float* attn = out + (size_t)BB * SS * EE;

    const size_t nBSE = (size_t)BB * SS * EE;   // 8388608 (== B*S*S)
    const size_t nEE  = (size_t)EE * EE;        // 1048576

    u16_t* p  = (u16_t*)d_ws;
    u16_t* qb  = p; p += nBSE;
    u16_t* kb  = p; p += nBSE;
    u16_t* vb  = p; p += nBSE;
    u16_t* Qp  = p; p += nBSE;
    u16_t* Kp  = p; p += nBSE;
    u16_t* Vp  = p; p += nBSE;
    u16_t* Xa  = p; p += nBSE;
    u16_t* Wqb = p; p += nEE;
    u16_t* Wkb = p; p += nEE;
    u16_t* Wvb = p; p += nEE;
    u16_t* Wob = p; p += nEE;

    // dead-region reuse after projections: Vt <- qb, maskb <- kb
    u16_t* Vt    = qb;
    u16_t* maskb = kb;

    cvt_f32_bf16<<<1024, 256, 0, stream>>>(query, qb, (int)(nBSE / 8));
    cvt_f32_bf16<<<1024, 256, 0, stream>>>(key,   kb, (int)(nBSE / 8));
    cvt_f32_bf16<<<1024, 256, 0, stream>>>(value, vb, (int)(nBSE / 8));
    cvt_f32_bf16<<<256,  256, 0, stream>>>(Wq, Wqb, (int)(nEE / 8));
    cvt_f32_bf16<<<256,  256, 0, stream>>>(Wk, Wkb, (int)(nEE / 8));
    cvt_f32_bf16<<<256,  256, 0, stream>>>(Wv, Wvb, (int)(nEE / 8));
    cvt_f32_bf16<<<256,  256, 0, stream>>>(Wo, Wob, (int)(nEE / 8));

    dim3 gProj(EE / 128, (BB * SS) / 128);   // (8, 64)
    gemm_bt<false><<<gProj, 256, 0, stream>>>(qb, Wqb, bq, (void*)Qp, BB * SS, EE, EE);
    gemm_bt<false><<<gProj, 256, 0, stream>>>(kb, Wkb, bk, (void*)Kp, BB * SS, EE, EE);
    gemm_bt<false><<<gProj, 256, 0, stream>>>(vb, Wvb, bv, (void*)Vp, BB * SS, EE, EE);

    dim3 gT(SS / 64, HH, BB);
    transpose_v<<<gT, 256, 0, stream>>>(Vp, Vt);
    cvt_mask<<<1024, 256, 0, stream>>>(mask, maskb, (int)(nBSE / 8));

    attn_fused<<<2048, 256, 0, stream>>>(Qp, Kp, Vt, maskb, adjoin, attn, Xa);

    gemm_bt<true><<<gProj, 256, 0, stream>>>(Xa, Wob, bo, (void*)out, BB * SS, EE, EE);
}